// Round 8
// baseline (98337.396 us; speedup 1.0000x reference)
//
#include <hip/hip_runtime.h>
#include <math.h>

#define BB_   64
#define TT_   256
#define DIN_  256
#define HH_   512
#define NMEM_ 128
#define WWID_ 64
#define RR_   4
#define DOUT_ 256
#define CTRL_ 512
#define EPSV  1e-8f
#define NBLK  64
#define NTHR  1024
#define IFLD  456   // ifc row stride (b-major layout)
#define MPAD  65    // padded mem stride: bank = (n+w)%32

__device__ __forceinline__ float sigm(float x){ return 1.f/(1.f+expf(-x)); }
__device__ __forceinline__ float softp(float x){ return (x>20.f)? x : log1pf(expf(x)); }
__device__ __forceinline__ float wredsum(float v){
  #pragma unroll
  for (int o=32;o>0;o>>=1) v += __shfl_xor(v,o,64);
  return v;
}
__device__ __forceinline__ float wredmax(float v){
  #pragma unroll
  for (int o=32;o>0;o>>=1) v = fmaxf(v, __shfl_xor(v,o,64));
  return v;
}

// ---- LLC-coherent accessors: relaxed agent-scope atomics (bypass per-XCD L2) ----
__device__ __forceinline__ float2 cload2(const float* p){
  unsigned long long u = __hip_atomic_load((const unsigned long long*)p,
                          __ATOMIC_RELAXED, __HIP_MEMORY_SCOPE_AGENT);
  float2 r; __builtin_memcpy(&r, &u, 8); return r;
}
__device__ __forceinline__ void cstore2(float* p, float2 v){
  unsigned long long u; __builtin_memcpy(&u, &v, 8);
  __hip_atomic_store((unsigned long long*)p, u, __ATOMIC_RELAXED,
                     __HIP_MEMORY_SCOPE_AGENT);
}
__device__ __forceinline__ void cstore1(float* p, float v){
  unsigned u; __builtin_memcpy(&u, &v, 4);
  __hip_atomic_store((unsigned*)p, u, __ATOMIC_RELAXED, __HIP_MEMORY_SCOPE_AGENT);
}

// ---- fence-free grid barrier: monotonic counters, 2-level tree (8 groups x 8) ----
__device__ __forceinline__ void gridbar(unsigned* bar, unsigned k)
{
  __syncthreads();
  if (threadIdx.x == 0) {
    const int g = blockIdx.x >> 3;
    unsigned a = __hip_atomic_fetch_add(bar + g*32, 1u, __ATOMIC_RELAXED,
                                        __HIP_MEMORY_SCOPE_AGENT);
    bool released = false;
    if (a == 8u*k - 1u) {
      unsigned r = __hip_atomic_fetch_add(bar + 256, 1u, __ATOMIC_RELAXED,
                                          __HIP_MEMORY_SCOPE_AGENT);
      if (r == 8u*k - 1u) {
        __hip_atomic_store(bar + 288, k, __ATOMIC_RELAXED,
                           __HIP_MEMORY_SCOPE_AGENT);
        released = true;
      }
    }
    if (!released) {
      while (__hip_atomic_load(bar + 288, __ATOMIC_RELAXED,
                               __HIP_MEMORY_SCOPE_AGENT) < k)
        __builtin_amdgcn_s_sleep(1);
    }
  }
  __syncthreads();
}

__global__ void k_initbar(unsigned* bar){
  int i = threadIdx.x;
  if (i < 320)
    __hip_atomic_store(bar + i, 0u, __ATOMIC_RELAXED, __HIP_MEMORY_SCOPE_AGENT);
}

struct Params {
  const float *x, *Wih, *Whh, *bih, *bhh, *Wint, *bint, *Wout, *bout;
  float *out;
  float *xbuf;   // 2 * 16384  (x_t packed [k/4][b][4])
  float *hp;     // 2 * 32768  (h packed)
  float *rvp;    // 16384      (rv packed)
  float *ifc;    // 64 * IFLD  ([b][o])
  unsigned *bar;
};

union SMu {
  float redA[8][32][64];     // 64 KB two-round gates reduction
  float redB[16][8][64];     // 32 KB iface reduction
  float redO[4][4][64];
  struct {
    float ifcS[IFLD];
    float kpk[WWID_][8];     // [w]: wkey, rk0..3, er, wvec, pad
    float dH[8][NMEM_];
    float qH[8][NMEM_];
    float nH[8][NMEM_];
    float drH[8][RR_][NMEM_];
    float wwS[NMEM_];
    float rwS[RR_][NMEM_];
    float rvH[16][64];
    float scal[8];
    float red2[8];
  } c;
};

__launch_bounds__(NTHR)
__global__ void k_persist(Params p)
{
  __shared__ SMu sm;
  __shared__ float memS[NMEM_][MPAD];   // persistent DNC memory

  const int bi  = blockIdx.x;
  const int tid = threadIdx.x;
  const int b   = tid & 63;
  const int wv  = tid >> 6;            // 0..15
  const int j0  = bi*8;

  float c_reg = 0.f;                   // LSTM cell state (tid<512)

  // Phase A weight bases: wave wv = K-slice of 64; 4 gate row-group bases
  const float* gbA[4];
  {
    const float* Wsrc = (wv < 8) ? p.Wih : p.Whh;
    const int koff = (wv & 7) * 64;
    #pragma unroll
    for (int g = 0; g < 4; ++g)
      gbA[g] = Wsrc + (size_t)(g*HH_ + j0)*CTRL_ + koff;
  }
  // Phase B weight rows (8 per block), wave wv = K-slice of 32
  const float* wbB[8];
  if (bi < 57) {
    #pragma unroll
    for (int r = 0; r < 8; ++r) {
      int o = bi*8 + r; if (o > 452) o = 452;
      wbB[r] = p.Wint + (size_t)o*HH_ + wv*32;
    }
  }
  float bsum[4];
  float bintB = 0.f;
  if (tid < 512) {
    const int j = j0 + (tid >> 6);
    #pragma unroll
    for (int g = 0; g < 4; ++g)
      bsum[g] = p.bih[g*HH_ + j] + p.bhh[g*HH_ + j];
    if (bi < 57) { int o = bi*8 + (tid >> 6); if (o < 453) bintB = p.bint[o]; }
  }

  // ---- init: zero h/rv, zero LDS memory, stage x_0 ----
  {
    const float2 zz = make_float2(0.f, 0.f);
    const int gt = bi*NTHR + tid;
    if      (gt < 32768) cstore2(p.hp  + 2*gt,          zz);
    else if (gt < 40960) cstore2(p.rvp + 2*(gt-32768),  zz);
    for (int i = tid; i < NMEM_*MPAD; i += NTHR)
      ((float*)memS)[i] = 0.f;
    if (bi >= 57) {
      const int g = (bi - 57)*NTHR + tid;
      if (g < 4096) {
        const int bb = g >> 6, kq = g & 63;
        float4 v = *(const float4*)(p.x + (size_t)bb*(TT_*DIN_) + 4*kq);
        float* d = p.xbuf + kq*256 + bb*4;
        cstore2(d,   make_float2(v.x, v.y));
        cstore2(d+2, make_float2(v.z, v.w));
      }
    }
  }
  unsigned bk = 1;
  gridbar(p.bar, bk);

  for (int t = 0; t < TT_; ++t) {
    const int cur = t & 1, nxt = cur ^ 1;
    const float* hR = p.hp + cur*32768;
    float*       hW = p.hp + nxt*32768;

    // ================= Phase A: gates GEMM + LSTM =================
    {
      const float* ap; int qs;
      if      (wv < 4) { ap = p.xbuf + cur*16384; qs = wv*16; }
      else if (wv < 8) { ap = p.rvp;              qs = (wv-4)*16; }
      else             { ap = hR;                 qs = (wv-8)*16; }

      float acc[32];
      #pragma unroll
      for (int r = 0; r < 32; ++r) acc[r] = 0.f;

      #pragma unroll 4
      for (int kk = 0; kk < 16; ++kk) {
        const float* a8 = ap + ((((qs + kk) << 6) + b) << 2);
        float2 alo = cload2(a8);
        float2 ahi = cload2(a8 + 2);
        #pragma unroll
        for (int g = 0; g < 4; ++g) {
          #pragma unroll
          for (int jj = 0; jj < 8; ++jj) {
            float4 w = *(const float4*)(gbA[g] + jj*CTRL_ + kk*4);
            acc[g*8+jj] += w.x*alo.x + w.y*alo.y + w.z*ahi.x + w.w*ahi.y;
          }
        }
      }
      if (wv < 8) {
        #pragma unroll
        for (int r = 0; r < 32; ++r) sm.redA[wv][r][b] = acc[r];
      }
      __syncthreads();
      if (wv >= 8) {
        #pragma unroll
        for (int r = 0; r < 32; ++r) sm.redA[wv-8][r][b] += acc[r];
      }
      __syncthreads();
      if (tid < 512) {
        const int jj = tid >> 6;
        float gs[4];
        #pragma unroll
        for (int g = 0; g < 4; ++g) {
          float s = bsum[g];
          #pragma unroll
          for (int p8 = 0; p8 < 8; ++p8) s += sm.redA[p8][g*8+jj][b];
          gs[g] = s;
        }
        float cn = sigm(gs[1])*c_reg + sigm(gs[0])*tanhf(gs[2]);
        c_reg = cn;
        float hn = sigm(gs[3])*tanhf(cn);
        const int j = j0 + jj;
        cstore1(hW + (j>>2)*256 + b*4 + (j&3), hn);
      }
    }
    gridbar(p.bar, ++bk);

    // ============ Phase B: iface GEMM (+ stage x_{t+1}) ============
    {
      if (bi < 57) {
        float accB[8];
        #pragma unroll
        for (int r = 0; r < 8; ++r) accB[r] = 0.f;
        #pragma unroll
        for (int kk = 0; kk < 8; ++kk) {
          const float* h8 = hW + (((((wv<<3) + kk) << 6) + b) << 2);
          float2 alo = cload2(h8);
          float2 ahi = cload2(h8 + 2);
          #pragma unroll
          for (int r = 0; r < 8; ++r) {
            float4 w = *(const float4*)(wbB[r] + kk*4);
            accB[r] += w.x*alo.x + w.y*alo.y + w.z*ahi.x + w.w*ahi.y;
          }
        }
        #pragma unroll
        for (int r = 0; r < 8; ++r) sm.redB[wv][r][b] = accB[r];
        __syncthreads();
        if (tid < 512) {
          const int rr = tid >> 6;
          const int o  = bi*8 + rr;
          if (o < 453) {
            float s = bintB;
            #pragma unroll
            for (int w16 = 0; w16 < 16; ++w16) s += sm.redB[w16][rr][b];
            cstore1(p.ifc + (size_t)b*IFLD + o, s);
          }
        }
      }
      if (bi >= 57 && t+1 < TT_) {
        const int g = (bi - 57)*NTHR + tid;
        if (g < 4096) {
          const int bb = g >> 6, kq = g & 63;
          float4 v = *(const float4*)(p.x + (size_t)bb*(TT_*DIN_)
                                      + (size_t)(t+1)*DIN_ + 4*kq);
          float* d = p.xbuf + nxt*16384 + kq*256 + bb*4;
          cstore2(d,   make_float2(v.x, v.y));
          cstore2(d+2, make_float2(v.z, v.w));
        }
      }
    }
    gridbar(p.bar, ++bk);

    // ========= Phase C: content addressing (lane = memory slot) =========
    {
      const int bb = bi;
      const int n  = tid & 127;
      const int wh = tid >> 7;      // 0..7 : w-slice of 8 words

      for (int i = tid; i < 228; i += NTHR) {
        float2 v = cload2(p.ifc + (size_t)bb*IFLD + 2*i);
        sm.c.ifcS[2*i]   = v.x;
        sm.c.ifcS[2*i+1] = v.y;
      }
      __syncthreads();

      if (tid < 64) {
        const int w = tid;
        float wk = sm.c.ifcS[260+w];
        float r0 = sm.c.ifcS[w],      r1 = sm.c.ifcS[64+w];
        float r2 = sm.c.ifcS[128+w],  r3 = sm.c.ifcS[192+w];
        float er  = sigm(sm.c.ifcS[325+w]);
        float wvc = sm.c.ifcS[389+w];
        sm.c.kpk[w][0]=wk; sm.c.kpk[w][1]=r0; sm.c.kpk[w][2]=r1; sm.c.kpk[w][3]=r2;
        sm.c.kpk[w][4]=r3; sm.c.kpk[w][5]=er; sm.c.kpk[w][6]=wvc; sm.c.kpk[w][7]=0.f;
        float s0 = wredsum(wk*wk);
        float s1 = wredsum(r0*r0);
        float s2 = wredsum(r1*r1);
        float s3 = wredsum(r2*r2);
        float s4 = wredsum(r3*r3);
        if (w == 0) {
          sm.c.scal[0] = fmaxf(sqrtf(s0), EPSV);
          sm.c.scal[1] = fmaxf(sqrtf(s1), EPSV);
          sm.c.scal[2] = fmaxf(sqrtf(s2), EPSV);
          sm.c.scal[3] = fmaxf(sqrtf(s3), EPSV);
          sm.c.scal[4] = fmaxf(sqrtf(s4), EPSV);
        }
      }
      __syncthreads();

      // pass1: write-key dot + pre-update norm (8-way w-split)
      {
        float dotw = 0.f, q = 0.f;
        const int w0 = wh*8;
        #pragma unroll
        for (int w = 0; w < 8; ++w) {
          float m = memS[n][w0+w];
          dotw += sm.c.kpk[w0+w][0]*m;
          q    += m*m;
        }
        sm.c.dH[wh][n] = dotw;
        sm.c.qH[wh][n] = q;
      }
      __syncthreads();

      // write softmax over 128 slots (tid<128)
      float a_n = 0.f, e_n = 0.f;
      const float wstr = softp(sm.c.ifcS[324]) + 1.f;
      if (tid < 128) {
        float dot = 0.f, q2 = 0.f;
        #pragma unroll
        for (int h = 0; h < 8; ++h) { dot += sm.c.dH[h][n]; q2 += sm.c.qH[h][n]; }
        a_n = wstr * dot / (sm.c.scal[0] * fmaxf(sqrtf(q2), EPSV));
        float mx = wredmax(a_n);
        if ((tid & 63) == 0) sm.c.red2[tid>>6] = mx;
      }
      __syncthreads();
      if (tid < 128) {
        float mx = fmaxf(sm.c.red2[0], sm.c.red2[1]);
        e_n = expf(a_n - mx);
        float s = wredsum(e_n);
        if ((tid & 63) == 0) sm.c.red2[4 + (tid>>6)] = s;
      }
      __syncthreads();
      if (tid < 128)
        sm.c.wwS[n] = e_n / (sm.c.red2[4] + sm.c.red2[5]);
      __syncthreads();

      // pass2: memory update + read-key dots + post norm
      {
        float ww_n = sm.c.wwS[n];
        float nrm=0.f, d0=0.f, d1=0.f, d2=0.f, d3=0.f;
        const int w0 = wh*8;
        #pragma unroll
        for (int w = 0; w < 8; ++w) {
          float4 k0 = *(const float4*)&sm.c.kpk[w0+w][0];
          float4 k1 = *(const float4*)&sm.c.kpk[w0+w][4];
          float m  = memS[n][w0+w];
          float mn = m*(1.f - ww_n*k1.y) + ww_n*k1.z;
          memS[n][w0+w] = mn;
          nrm += mn*mn;
          d0 += k0.y*mn; d1 += k0.z*mn; d2 += k0.w*mn; d3 += k1.x*mn;
        }
        sm.c.nH[wh][n] = nrm;
        sm.c.drH[wh][0][n]=d0; sm.c.drH[wh][1][n]=d1;
        sm.c.drH[wh][2][n]=d2; sm.c.drH[wh][3][n]=d3;
      }
      __syncthreads();

      // read scores (tid<128)
      if (tid < 128) {
        float nrm = 0.f;
        #pragma unroll
        for (int h = 0; h < 8; ++h) nrm += sm.c.nH[h][n];
        float inm = 1.f / fmaxf(sqrtf(nrm), EPSV);
        #pragma unroll
        for (int r = 0; r < RR_; ++r) {
          float rstr = softp(sm.c.ifcS[256+r]) + 1.f;
          float dr = 0.f;
          #pragma unroll
          for (int h = 0; h < 8; ++h) dr += sm.c.drH[h][r][n];
          sm.c.rwS[r][n] = rstr * dr * inm / sm.c.scal[1+r];
        }
      }
      __syncthreads();

      // read softmaxes: waves 0..3 = heads
      if (tid < 256) {
        float v0 = sm.c.rwS[wv][b], v1 = sm.c.rwS[wv][b+64];
        float mx = wredmax(fmaxf(v0, v1));
        float e0 = expf(v0-mx), e1 = expf(v1-mx);
        float s  = wredsum(e0+e1);
        sm.c.rwS[wv][b]    = e0/s;
        sm.c.rwS[wv][b+64] = e1/s;
      }
      __syncthreads();

      // rv partials: wave wv -> head wv>>2, n-quarter wv&3
      {
        const int r  = wv >> 2, q4 = wv & 3;
        float acc = 0.f;
        #pragma unroll 2
        for (int n2 = q4*32; n2 < q4*32 + 32; n2 += 4) {
          float4 r4 = *(const float4*)&sm.c.rwS[r][n2];
          acc += r4.x*memS[n2][b]   + r4.y*memS[n2+1][b]
               + r4.z*memS[n2+2][b] + r4.w*memS[n2+3][b];
        }
        sm.c.rvH[wv][b] = acc;
      }
      __syncthreads();
      if (tid < 256) {
        const int r = tid >> 6;
        float acc = sm.c.rvH[r*4][b] + sm.c.rvH[r*4+1][b]
                  + sm.c.rvH[r*4+2][b] + sm.c.rvH[r*4+3][b];
        const int k = r*64 + b;
        cstore1(p.rvp + (k>>2)*256 + bb*4 + (k&3), acc);
      }
    }
    gridbar(p.bar, ++bk);
  }

  // ================= Output projection (last step only) =================
  {
    const int o0 = bi*4;
    if (tid < 256) {
      float acc[4] = {0.f, 0.f, 0.f, 0.f};
      #pragma unroll 4
      for (int kk = 0; kk < 48; ++kk) {
        const int k = wv*192 + kk*4;
        const float* a8 = (k < 512)
          ? (p.hp  + ((((k    )>>2) << 6) + b)*4)   // TT even -> final h in hp[0]
          : (p.rvp + ((((k-512)>>2) << 6) + b)*4);
        float2 alo = cload2(a8);
        float2 ahi = cload2(a8 + 2);
        #pragma unroll
        for (int r = 0; r < 4; ++r) {
          float4 w = *(const float4*)(p.Wout + (size_t)(o0+r)*(HH_ + RR_*WWID_) + k);
          acc[r] += w.x*alo.x + w.y*alo.y + w.z*ahi.x + w.w*ahi.y;
        }
      }
      #pragma unroll
      for (int r = 0; r < 4; ++r) sm.redO[wv][r][b] = acc[r];
    }
    __syncthreads();
    if (tid < 64) {
      float4 o4;
      float* po = (float*)&o4;
      #pragma unroll
      for (int r = 0; r < 4; ++r)
        po[r] = sm.redO[0][r][b] + sm.redO[1][r][b] + sm.redO[2][r][b]
              + sm.redO[3][r][b] + p.bout[o0+r];
      *(float4*)(p.out + (size_t)b*DOUT_ + o0) = o4;
    }
  }
}

extern "C" void kernel_launch(void* const* d_in, const int* in_sizes, int n_in,
                              void* d_out, int out_size, void* d_ws, size_t ws_size,
                              hipStream_t stream)
{
  Params prm;
  prm.x    = (const float*)d_in[0];
  prm.Wih  = (const float*)d_in[1];
  prm.Whh  = (const float*)d_in[2];
  prm.bih  = (const float*)d_in[3];
  prm.bhh  = (const float*)d_in[4];
  prm.Wint = (const float*)d_in[5];
  prm.bint = (const float*)d_in[6];
  prm.Wout = (const float*)d_in[7];
  prm.bout = (const float*)d_in[8];
  prm.out  = (float*)d_out;

  float* ws = (float*)d_ws;
  size_t off = 0;
  prm.xbuf = ws + off; off += 2*16384;
  prm.hp   = ws + off; off += 2*32768;
  prm.rvp  = ws + off; off += 16384;
  prm.ifc  = ws + off; off += 64*IFLD;
  prm.bar  = (unsigned*)(ws + off); off += 512;

  k_initbar<<<1, 512, 0, stream>>>(prm.bar);
  k_persist<<<NBLK, NTHR, 0, stream>>>(prm);
}

// Round 9
// 18152.188 us; speedup vs baseline: 5.4174x; 5.4174x over previous
//
#include <hip/hip_runtime.h>
#include <math.h>

#define BB_   64
#define TT_   256
#define DIN_  256
#define HH_   512
#define NMEM_ 128
#define WWID_ 64
#define RR_   4
#define DOUT_ 256
#define CTRL_ 512
#define EPSV  1e-8f
#define NBLK  128
#define NTHR  512
#define IFLD  456
#define MPAD  65    // padded mem stride: bank = (n+w)%32

__device__ __forceinline__ float sigm(float x){ return 1.f/(1.f+expf(-x)); }
__device__ __forceinline__ float softp(float x){ return (x>20.f)? x : log1pf(expf(x)); }
__device__ __forceinline__ float wredsum(float v){
  #pragma unroll
  for (int o=32;o>0;o>>=1) v += __shfl_xor(v,o,64);
  return v;
}
__device__ __forceinline__ float wredmax(float v){
  #pragma unroll
  for (int o=32;o>0;o>>=1) v = fmaxf(v, __shfl_xor(v,o,64));
  return v;
}

// ---- LLC-coherent accessors: relaxed agent-scope atomics (bypass per-XCD L2) ----
__device__ __forceinline__ float2 cload2(const float* p){
  unsigned long long u = __hip_atomic_load((const unsigned long long*)p,
                          __ATOMIC_RELAXED, __HIP_MEMORY_SCOPE_AGENT);
  float2 r; __builtin_memcpy(&r, &u, 8); return r;
}
__device__ __forceinline__ void cstore2(float* p, float2 v){
  unsigned long long u; __builtin_memcpy(&u, &v, 8);
  __hip_atomic_store((unsigned long long*)p, u, __ATOMIC_RELAXED,
                     __HIP_MEMORY_SCOPE_AGENT);
}
__device__ __forceinline__ void cstore1(float* p, float v){
  unsigned u; __builtin_memcpy(&u, &v, 4);
  __hip_atomic_store((unsigned*)p, u, __ATOMIC_RELAXED, __HIP_MEMORY_SCOPE_AGENT);
}

// ---- fence-free grid barrier: monotonic counters, 16 groups x 8 blocks ----
__device__ __forceinline__ void gridbar(unsigned* bar, unsigned k)
{
  __syncthreads();
  if (threadIdx.x == 0) {
    const int g = blockIdx.x >> 3;
    unsigned a = __hip_atomic_fetch_add(bar + g*32, 1u, __ATOMIC_RELAXED,
                                        __HIP_MEMORY_SCOPE_AGENT);
    bool released = false;
    if (a == 8u*k - 1u) {
      unsigned r = __hip_atomic_fetch_add(bar + 512, 1u, __ATOMIC_RELAXED,
                                          __HIP_MEMORY_SCOPE_AGENT);
      if (r == 16u*k - 1u) {
        __hip_atomic_store(bar + 544, k, __ATOMIC_RELAXED,
                           __HIP_MEMORY_SCOPE_AGENT);
        released = true;
      }
    }
    if (!released) {
      while (__hip_atomic_load(bar + 544, __ATOMIC_RELAXED,
                               __HIP_MEMORY_SCOPE_AGENT) < k)
        __builtin_amdgcn_s_sleep(1);
    }
  }
  __syncthreads();
}

__global__ void k_initbar(unsigned* bar){
  int i = threadIdx.x;
  if (i < 576)
    __hip_atomic_store(bar + i, 0u, __ATOMIC_RELAXED, __HIP_MEMORY_SCOPE_AGENT);
}

struct Params {
  const float *x, *Wih, *Whh, *bih, *bhh, *Wint, *bint, *Wout, *bout;
  float *out;
  float *xbuf;   // 2 * 16384  (x_t packed [k/4][b][4])
  float *hp;     // 2 * 32768  (h packed)
  float *rvp;    // 16384      (rv packed)
  unsigned *bar;
};

union SMu {
  float4 actS[4096];            // 64 KB staged activation chunk (Phase A)
  float  gsS[16][64];           // gate-row dots (aliases actS; used post-sync)
  float  redO[4][4][64];        // output projection reduce
  struct {
    float hS[512];              // this batch's h
    float ifcS[IFLD];           // iface row (computed in-block)
    float kpk[WWID_][8];        // [w]: wkey, rk0..3, er, wvec, pad
    float dH[4][NMEM_];
    float qH[4][NMEM_];
    float nH[4][NMEM_];
    float drH[4][RR_][NMEM_];
    float wwS[NMEM_];
    float rwS[RR_][NMEM_];
    float rvH[8][64];
    float scal[8];
    float red2[8];
  } c;
};

__launch_bounds__(NTHR, 2)
__global__ void k_persist(Params p)
{
  __shared__ SMu sm;
  __shared__ float memS[NMEM_][MPAD];   // persistent DNC memory (bi<64)

  const int bi  = blockIdx.x;
  const int tid = threadIdx.x;
  const int b   = tid & 63;
  const int wv  = tid >> 6;            // 0..7
  const int bb  = bi;                  // batch id for Phase C (bi<64)

  float c_reg = 0.f;                   // LSTM cell state (tid<256)

  // Phase A: wave wv owns gate-rows r0=2wv, r1=2wv+1 of this block's 16.
  // row r: gate g=r>>2, jj=r&3, W-row = g*HH_ + bi*4 + jj  (full K kept per wave)
  const int r0 = 2*wv, r1 = r0 + 1;
  const int wrow0 = (r0>>2)*HH_ + bi*4 + (r0&3);
  const int wrow1 = (r1>>2)*HH_ + bi*4 + (r1&3);

  float bsum[4];
  if (tid < 256) {
    const int j = bi*4 + (tid>>6);
    #pragma unroll
    for (int g = 0; g < 4; ++g)
      bsum[g] = p.bih[g*HH_ + j] + p.bhh[g*HH_ + j];
  }
  float bintR = 0.f;
  if (bi < 64 && tid < 453) bintR = p.bint[tid];

  // ---- init: zero h0/rv, zero memS, stage x_0 ----
  {
    const float2 zz = make_float2(0.f, 0.f);
    const int gt = bi*NTHR + tid;
    if      (gt < 16384) cstore2(p.hp  + 2*gt,         zz);
    else if (gt < 24576) cstore2(p.rvp + 2*(gt-16384), zz);
    if (bi < 64)
      for (int i = tid; i < NMEM_*MPAD; i += NTHR)
        ((float*)memS)[i] = 0.f;
    if (bi >= 64 && tid < 64) {
      const int B = bi - 64;
      float4 v = *(const float4*)(p.x + (size_t)B*(TT_*DIN_) + 4*tid);
      float* d = p.xbuf + tid*256 + B*4;
      cstore2(d,   make_float2(v.x, v.y));
      cstore2(d+2, make_float2(v.z, v.w));
    }
  }
  unsigned bk = 1;
  gridbar(p.bar, bk);

  for (int t = 0; t < TT_; ++t) {
    const int cur = t & 1, nxt = cur ^ 1;
    const float* hR = p.hp + cur*32768;
    float*       hW = p.hp + nxt*32768;

    // ================= Phase A: gates GEMM + LSTM =================
    {
      float acc0 = 0.f, acc1 = 0.f;
      #pragma unroll 1
      for (int c = 0; c < 4; ++c) {
        const float* src = (c==0) ? (p.xbuf + cur*16384)
                         : (c==1) ? p.rvp
                         : (c==2) ? hR : (hR + 16384);
        // stage 64 KB chunk (coalesced: lanes contiguous float4)
        #pragma unroll
        for (int i = 0; i < 8; ++i) {
          const int fi = tid + (i<<9);
          const float* s4 = src + 4*fi;
          float2 lo = cload2(s4), hi = cload2(s4 + 2);
          sm.actS[fi] = make_float4(lo.x, lo.y, hi.x, hi.y);
        }
        __syncthreads();
        const float* wbase = (c < 2) ? p.Wih : p.Whh;
        const int    koff  = (c & 1) * 256;
        const float* w0p = wbase + (size_t)wrow0*CTRL_ + koff;
        const float* w1p = wbase + (size_t)wrow1*CTRL_ + koff;
        #pragma unroll 8
        for (int k4 = 0; k4 < 64; ++k4) {
          float4 a  = sm.actS[(k4<<6) + b];          // ds_read_b128
          float4 w0 = *(const float4*)(w0p + (k4<<2));  // uniform, L2-warm
          float4 w1 = *(const float4*)(w1p + (k4<<2));
          acc0 += w0.x*a.x + w0.y*a.y + w0.z*a.z + w0.w*a.w;
          acc1 += w1.x*a.x + w1.y*a.y + w1.z*a.z + w1.w*a.w;
        }
        __syncthreads();
      }
      sm.gsS[r0][b] = acc0;     // aliases actS; all reads complete
      sm.gsS[r1][b] = acc1;
      __syncthreads();
      if (tid < 256) {
        const int jj = tid >> 6;
        float gs[4];
        #pragma unroll
        for (int g = 0; g < 4; ++g)
          gs[g] = sm.gsS[g*4 + jj][b] + bsum[g];
        float cn = sigm(gs[1])*c_reg + sigm(gs[0])*tanhf(gs[2]);
        c_reg = cn;
        float hn = sigm(gs[3])*tanhf(cn);
        cstore1(hW + bi*256 + b*4 + jj, hn);
      }
    }
    gridbar(p.bar, ++bk);

    // ====== Phase C: iface (in-block) + content addressing | x-staging ======
    if (bi < 64) {
      // stage h[bb]
      if (tid < 128) {
        const float* hsrc = hW + tid*256 + bb*4;
        float2 lo = cload2(hsrc), hi = cload2(hsrc + 2);
        sm.c.hS[4*tid]   = lo.x; sm.c.hS[4*tid+1] = lo.y;
        sm.c.hS[4*tid+2] = hi.x; sm.c.hS[4*tid+3] = hi.y;
      }
      __syncthreads();
      // iface row for this batch: thread = output o
      if (tid < 453) {
        const float* wr = p.Wint + (size_t)tid*HH_;
        float acc = bintR;
        #pragma unroll 4
        for (int k4 = 0; k4 < 128; ++k4) {
          float4 w  = *(const float4*)(wr + 4*k4);
          float4 h4 = *(const float4*)&sm.c.hS[4*k4];
          acc += w.x*h4.x + w.y*h4.y + w.z*h4.z + w.w*h4.w;
        }
        sm.c.ifcS[tid] = acc;
      }
      __syncthreads();

      // key pack + key norms (wave 0)
      if (tid < 64) {
        const int w = tid;
        float wk = sm.c.ifcS[260+w];
        float q0 = sm.c.ifcS[w],      q1 = sm.c.ifcS[64+w];
        float q2 = sm.c.ifcS[128+w],  q3 = sm.c.ifcS[192+w];
        float er  = sigm(sm.c.ifcS[325+w]);
        float wvc = sm.c.ifcS[389+w];
        sm.c.kpk[w][0]=wk; sm.c.kpk[w][1]=q0; sm.c.kpk[w][2]=q1; sm.c.kpk[w][3]=q2;
        sm.c.kpk[w][4]=q3; sm.c.kpk[w][5]=er; sm.c.kpk[w][6]=wvc; sm.c.kpk[w][7]=0.f;
        float s0 = wredsum(wk*wk);
        float s1 = wredsum(q0*q0);
        float s2 = wredsum(q1*q1);
        float s3 = wredsum(q2*q2);
        float s4 = wredsum(q3*q3);
        if (w == 0) {
          sm.c.scal[0] = fmaxf(sqrtf(s0), EPSV);
          sm.c.scal[1] = fmaxf(sqrtf(s1), EPSV);
          sm.c.scal[2] = fmaxf(sqrtf(s2), EPSV);
          sm.c.scal[3] = fmaxf(sqrtf(s3), EPSV);
          sm.c.scal[4] = fmaxf(sqrtf(s4), EPSV);
        }
      }
      __syncthreads();

      const int n  = tid & 127;
      const int wh = tid >> 7;      // 0..3 : w-slice of 16

      // pass1: write-key dot + pre-update norm
      {
        float dotw = 0.f, q = 0.f;
        const int w0 = wh*16;
        #pragma unroll
        for (int w = 0; w < 16; ++w) {
          float m = memS[n][w0+w];
          dotw += sm.c.kpk[w0+w][0]*m;
          q    += m*m;
        }
        sm.c.dH[wh][n] = dotw;
        sm.c.qH[wh][n] = q;
      }
      __syncthreads();

      // write softmax over 128 slots (tid<128)
      float a_n = 0.f, e_n = 0.f;
      const float wstr = softp(sm.c.ifcS[324]) + 1.f;
      if (tid < 128) {
        float dot = sm.c.dH[0][n] + sm.c.dH[1][n] + sm.c.dH[2][n] + sm.c.dH[3][n];
        float q2  = sm.c.qH[0][n] + sm.c.qH[1][n] + sm.c.qH[2][n] + sm.c.qH[3][n];
        a_n = wstr * dot / (sm.c.scal[0] * fmaxf(sqrtf(q2), EPSV));
        float mx = wredmax(a_n);
        if ((tid & 63) == 0) sm.c.red2[tid>>6] = mx;
      }
      __syncthreads();
      if (tid < 128) {
        float mx = fmaxf(sm.c.red2[0], sm.c.red2[1]);
        e_n = expf(a_n - mx);
        float s = wredsum(e_n);
        if ((tid & 63) == 0) sm.c.red2[4 + (tid>>6)] = s;
      }
      __syncthreads();
      if (tid < 128)
        sm.c.wwS[n] = e_n / (sm.c.red2[4] + sm.c.red2[5]);
      __syncthreads();

      // pass2: memory update + read-key dots + post norm
      {
        float ww_n = sm.c.wwS[n];
        float nrm=0.f, d0=0.f, d1=0.f, d2=0.f, d3=0.f;
        const int w0 = wh*16;
        #pragma unroll
        for (int w = 0; w < 16; ++w) {
          float4 k0 = *(const float4*)&sm.c.kpk[w0+w][0];
          float4 k1 = *(const float4*)&sm.c.kpk[w0+w][4];
          float m  = memS[n][w0+w];
          float mn = m*(1.f - ww_n*k1.y) + ww_n*k1.z;
          memS[n][w0+w] = mn;
          nrm += mn*mn;
          d0 += k0.y*mn; d1 += k0.z*mn; d2 += k0.w*mn; d3 += k1.x*mn;
        }
        sm.c.nH[wh][n] = nrm;
        sm.c.drH[wh][0][n]=d0; sm.c.drH[wh][1][n]=d1;
        sm.c.drH[wh][2][n]=d2; sm.c.drH[wh][3][n]=d3;
      }
      __syncthreads();

      // read scores (tid<128)
      if (tid < 128) {
        float nrm = sm.c.nH[0][n] + sm.c.nH[1][n] + sm.c.nH[2][n] + sm.c.nH[3][n];
        float inm = 1.f / fmaxf(sqrtf(nrm), EPSV);
        #pragma unroll
        for (int r = 0; r < RR_; ++r) {
          float rstr = softp(sm.c.ifcS[256+r]) + 1.f;
          float dr = sm.c.drH[0][r][n] + sm.c.drH[1][r][n]
                   + sm.c.drH[2][r][n] + sm.c.drH[3][r][n];
          sm.c.rwS[r][n] = rstr * dr * inm / sm.c.scal[1+r];
        }
      }
      __syncthreads();

      // read softmaxes: waves 0..3 = heads
      if (tid < 256) {
        float v0 = sm.c.rwS[wv][b], v1 = sm.c.rwS[wv][b+64];
        float mx = wredmax(fmaxf(v0, v1));
        float e0 = expf(v0-mx), e1 = expf(v1-mx);
        float s  = wredsum(e0+e1);
        sm.c.rwS[wv][b]    = e0/s;
        sm.c.rwS[wv][b+64] = e1/s;
      }
      __syncthreads();

      // rv partials: wave wv -> head wv>>1, n-half wv&1
      {
        const int r  = wv >> 1;
        const int n0 = (wv & 1) * 64;
        float acc = 0.f;
        #pragma unroll 4
        for (int n2 = n0; n2 < n0 + 64; n2 += 4) {
          float4 r4 = *(const float4*)&sm.c.rwS[r][n2];
          acc += r4.x*memS[n2][b]   + r4.y*memS[n2+1][b]
               + r4.z*memS[n2+2][b] + r4.w*memS[n2+3][b];
        }
        sm.c.rvH[wv][b] = acc;
      }
      __syncthreads();
      if (tid < 256) {
        const int r = tid >> 6;
        float acc = sm.c.rvH[2*r][b] + sm.c.rvH[2*r+1][b];
        const int k = r*64 + b;
        cstore1(p.rvp + (k>>2)*256 + bb*4 + (k&3), acc);
      }
    } else {
      // stage x_{t+1} (block 64+B owns batch B's row)
      if (t+1 < TT_ && tid < 64) {
        const int B = bi - 64;
        float4 v = *(const float4*)(p.x + (size_t)B*(TT_*DIN_)
                                    + (size_t)(t+1)*DIN_ + 4*tid);
        float* d = p.xbuf + nxt*16384 + tid*256 + B*4;
        cstore2(d,   make_float2(v.x, v.y));
        cstore2(d+2, make_float2(v.z, v.w));
      }
    }
    gridbar(p.bar, ++bk);
  }

  // ================= Output projection (last step only) =================
  if (bi < 64) {
    const int o0 = bi*4;
    if (tid < 256) {
      float acc[4] = {0.f, 0.f, 0.f, 0.f};
      #pragma unroll 4
      for (int kk = 0; kk < 48; ++kk) {
        const int k = wv*192 + kk*4;
        const float* a8 = (k < 512)
          ? (p.hp  + (((k    )>>2)*64 + b)*4)    // TT even -> final h in hp[0]
          : (p.rvp + (((k-512)>>2)*64 + b)*4);
        float2 alo = cload2(a8);
        float2 ahi = cload2(a8 + 2);
        #pragma unroll
        for (int r = 0; r < 4; ++r) {
          float4 w = *(const float4*)(p.Wout + (size_t)(o0+r)*(HH_ + RR_*WWID_) + k);
          acc[r] += w.x*alo.x + w.y*alo.y + w.z*ahi.x + w.w*ahi.y;
        }
      }
      #pragma unroll
      for (int r = 0; r < 4; ++r) sm.redO[wv][r][b] = acc[r];
    }
    __syncthreads();
    if (tid < 64) {
      float4 o4;
      float* po = (float*)&o4;
      #pragma unroll
      for (int r = 0; r < 4; ++r)
        po[r] = sm.redO[0][r][b] + sm.redO[1][r][b] + sm.redO[2][r][b]
              + sm.redO[3][r][b] + p.bout[o0+r];
      *(float4*)(p.out + (size_t)b*DOUT_ + o0) = o4;
    }
  }
}

extern "C" void kernel_launch(void* const* d_in, const int* in_sizes, int n_in,
                              void* d_out, int out_size, void* d_ws, size_t ws_size,
                              hipStream_t stream)
{
  Params prm;
  prm.x    = (const float*)d_in[0];
  prm.Wih  = (const float*)d_in[1];
  prm.Whh  = (const float*)d_in[2];
  prm.bih  = (const float*)d_in[3];
  prm.bhh  = (const float*)d_in[4];
  prm.Wint = (const float*)d_in[5];
  prm.bint = (const float*)d_in[6];
  prm.Wout = (const float*)d_in[7];
  prm.bout = (const float*)d_in[8];
  prm.out  = (float*)d_out;

  float* ws = (float*)d_ws;
  size_t off = 0;
  prm.xbuf = ws + off; off += 2*16384;
  prm.hp   = ws + off; off += 2*32768;
  prm.rvp  = ws + off; off += 16384;
  prm.bar  = (unsigned*)(ws + off); off += 1024;

  k_initbar<<<1, 576, 0, stream>>>(prm.bar);
  k_persist<<<NBLK, NTHR, 0, stream>>>(prm);
}

// Round 10
// 9406.860 us; speedup vs baseline: 10.4538x; 1.9297x over previous
//
#include <hip/hip_runtime.h>
#include <math.h>

#define BB_   64
#define TT_   256
#define DIN_  256
#define HH_   512
#define NMEM_ 128
#define WWID_ 64
#define RR_   4
#define DOUT_ 256
#define CTRL_ 512
#define EPSV  1e-8f
#define NBLK  256
#define NTHR  512
#define OSTR  456   // W_intT4 o-stride
#define MPAD  65    // padded mem stride

__device__ __forceinline__ float sigm(float x){ return 1.f/(1.f+expf(-x)); }
__device__ __forceinline__ float softp(float x){ return (x>20.f)? x : log1pf(expf(x)); }
__device__ __forceinline__ float wredsum(float v){
  #pragma unroll
  for (int o=32;o>0;o>>=1) v += __shfl_xor(v,o,64);
  return v;
}
__device__ __forceinline__ float wredmax(float v){
  #pragma unroll
  for (int o=32;o>0;o>>=1) v = fmaxf(v, __shfl_xor(v,o,64));
  return v;
}

// ---- LLC-coherent accessors: relaxed agent-scope atomics (bypass per-XCD L2) ----
__device__ __forceinline__ float2 cload2(const float* p){
  unsigned long long u = __hip_atomic_load((const unsigned long long*)p,
                          __ATOMIC_RELAXED, __HIP_MEMORY_SCOPE_AGENT);
  float2 r; __builtin_memcpy(&r, &u, 8); return r;
}
__device__ __forceinline__ void cstore2(float* p, float2 v){
  unsigned long long u; __builtin_memcpy(&u, &v, 8);
  __hip_atomic_store((unsigned long long*)p, u, __ATOMIC_RELAXED,
                     __HIP_MEMORY_SCOPE_AGENT);
}
__device__ __forceinline__ void cstore1(float* p, float v){
  unsigned u; __builtin_memcpy(&u, &v, 4);
  __hip_atomic_store((unsigned*)p, u, __ATOMIC_RELAXED, __HIP_MEMORY_SCOPE_AGENT);
}

// ---- fence-free grid barrier: monotonic counters, 32 groups x 8 blocks ----
__device__ __forceinline__ void gridbar(unsigned* bar, unsigned k)
{
  __syncthreads();
  if (threadIdx.x == 0) {
    const int g = blockIdx.x >> 3;
    unsigned a = __hip_atomic_fetch_add(bar + g*32, 1u, __ATOMIC_RELAXED,
                                        __HIP_MEMORY_SCOPE_AGENT);
    bool released = false;
    if (a == 8u*k - 1u) {
      unsigned r = __hip_atomic_fetch_add(bar + 1024, 1u, __ATOMIC_RELAXED,
                                          __HIP_MEMORY_SCOPE_AGENT);
      if (r == 32u*k - 1u) {
        __hip_atomic_store(bar + 1056, k, __ATOMIC_RELAXED,
                           __HIP_MEMORY_SCOPE_AGENT);
        released = true;
      }
    }
    if (!released) {
      while (__hip_atomic_load(bar + 1056, __ATOMIC_RELAXED,
                               __HIP_MEMORY_SCOPE_AGENT) < k)
        __builtin_amdgcn_s_sleep(1);
    }
  }
  __syncthreads();
}

__global__ void k_initbar(unsigned* bar){
  int i = blockIdx.x*256 + threadIdx.x;
  if (i < 1088)
    __hip_atomic_store(bar + i, 0u, __ATOMIC_RELAXED, __HIP_MEMORY_SCOPE_AGENT);
}

// one-time: W_intT4[kq][o][c] = W_int[o][4kq+c]  (plain; kernel boundary = fence)
__global__ void k_prep_w(const float* __restrict__ Wint, float* __restrict__ WiT4){
  const int o  = blockIdx.x;        // 0..452
  const int kq = threadIdx.x;       // 0..127
  float4 v = *(const float4*)(Wint + (size_t)o*HH_ + 4*kq);
  *(float4*)(WiT4 + ((size_t)kq*OSTR + o)*4) = v;
}

struct Params {
  const float *x, *Wih, *Whh, *bih, *bhh, *bint, *Wout, *bout;
  float *out;
  float *xbuf;   // 2 * 16384  (x_t packed [kq][b][4])
  float *hp;     // 2 * 32768  (h packed [j/4][b][4])
  float *rvp;    // 16384      (rv packed)
  float *WiT4;   // 128*456*4
  unsigned *bar;
};

union __align__(16) SMu {
  float redA[8][8][64];         // 16 KB gates reduction
  float redO[4][4][64];
  struct {
    float hS[HH_];              // this batch's h
    float ifcS[OSTR];           // iface row (in-block)
    float kpk[WWID_][8];        // [w]: wkey, rk0..3, er, wvec, pad
    float dH[4][NMEM_];
    float qH[4][NMEM_];
    float nH[4][NMEM_];
    float drH[4][RR_][NMEM_];
    float wwS[NMEM_];
    float rwS[RR_][NMEM_];
    float rvH[8][64];
    float scal[8];
    float red2[8];
  } c;
};

__launch_bounds__(NTHR, 2)
__global__ void k_persist(Params p)
{
  __shared__ SMu sm;
  __shared__ float memS[NMEM_][MPAD];   // persistent DNC memory (bi<64)

  const int bi  = blockIdx.x;
  const int tid = threadIdx.x;
  const int b   = tid & 63;
  const int wv  = tid >> 6;            // 0..7
  const int j0  = bi*2;                // this block's 2 hidden units
  const int bb  = bi;                  // batch id (bi<64)

  float c_reg = 0.f;                   // LSTM cell state (tid<128)

  // Phase A: 8 rows (4 gates x 2 units); wave = K-slice of 128
  // row r: gate g=r>>1, jj=r&1 -> W-row g*HH_ + j0 + jj
  const float* ap_sel;                 // activation source (per wave)
  const float* wb[8];
  int qbase;
  {
    const float* wsrc; int koff;
    if      (wv < 2) { wsrc = p.Wih; koff = wv*128;            qbase = wv*32; }
    else if (wv < 4) { wsrc = p.Wih; koff = 256 + (wv-2)*128;  qbase = (wv-2)*32; }
    else             { wsrc = p.Whh; koff = (wv-4)*128;        qbase = (wv-4)*32; }
    #pragma unroll
    for (int r = 0; r < 8; ++r)
      wb[r] = wsrc + (size_t)((r>>1)*HH_ + j0 + (r&1))*CTRL_ + koff;
    ap_sel = nullptr; (void)ap_sel;
  }

  float bsum[4];
  if (tid < 128) {
    const int j = j0 + (tid >> 6);
    #pragma unroll
    for (int g = 0; g < 4; ++g)
      bsum[g] = p.bih[g*HH_ + j] + p.bhh[g*HH_ + j];
  }
  float bintR = 0.f;
  if (bi < 64 && tid < 453) bintR = p.bint[tid];

  // ---- init: zero h0/rv, zero memS, stage x_0 ----
  {
    const float2 zz = make_float2(0.f, 0.f);
    const int gt = bi*NTHR + tid;
    if      (gt < 16384) cstore2(p.hp  + 2*gt,         zz);   // h buffer 0
    else if (gt < 24576) cstore2(p.rvp + 2*(gt-16384), zz);
    if (bi < 64)
      for (int i = tid; i < NMEM_*MPAD; i += NTHR)
        ((float*)memS)[i] = 0.f;
    if (bi >= 64 && bi < 128 && tid < 64) {
      const int B = bi - 64;
      float4 v = *(const float4*)(p.x + (size_t)B*(TT_*DIN_) + 4*tid);
      float* d = p.xbuf + tid*256 + B*4;
      cstore2(d,   make_float2(v.x, v.y));
      cstore2(d+2, make_float2(v.z, v.w));
    }
  }
  unsigned bk = 1;
  gridbar(p.bar, bk);

  for (int t = 0; t < TT_; ++t) {
    const int cur = t & 1, nxt = cur ^ 1;
    const float* hR = p.hp + cur*32768;
    float*       hW = p.hp + nxt*32768;

    // ================= Phase A: gates GEMM + LSTM =================
    {
      const float* ap = (wv < 2) ? (p.xbuf + cur*16384)
                       : (wv < 4) ? p.rvp : hR;

      float acc[8];
      #pragma unroll
      for (int r = 0; r < 8; ++r) acc[r] = 0.f;

      #pragma unroll 4
      for (int kk = 0; kk < 32; ++kk) {
        const float* a8 = ap + (((qbase + kk) << 6) + b)*4;
        float2 alo = cload2(a8);
        float2 ahi = cload2(a8 + 2);
        #pragma unroll
        for (int r = 0; r < 8; ++r) {
          float4 w = *(const float4*)(wb[r] + (kk << 2));   // uniform, L2-warm
          acc[r] += w.x*alo.x + w.y*alo.y + w.z*ahi.x + w.w*ahi.y;
        }
      }
      #pragma unroll
      for (int r = 0; r < 8; ++r) sm.redA[wv][r][b] = acc[r];
      __syncthreads();

      if (tid < 128) {
        const int jj = tid >> 6;
        const int j  = j0 + jj;
        float gs[4];
        #pragma unroll
        for (int g = 0; g < 4; ++g) {
          float s = bsum[g];
          #pragma unroll
          for (int w8 = 0; w8 < 8; ++w8) s += sm.redA[w8][g*2+jj][b];
          gs[g] = s;
        }
        float cn = sigm(gs[1])*c_reg + sigm(gs[0])*tanhf(gs[2]);
        c_reg = cn;
        float hn = sigm(gs[3])*tanhf(cn);
        cstore1(hW + (j>>2)*256 + b*4 + (j&3), hn);
      }
    }
    gridbar(p.bar, ++bk);

    // ====== Phase BC: iface (in-block, transposed W) + addressing ======
    if (bi < 64) {
      // stage this batch's h (coherent)
      if (tid < 128) {
        const float* hsrc = hW + tid*256 + bb*4;
        float2 lo = cload2(hsrc), hi = cload2(hsrc + 2);
        sm.c.hS[4*tid]   = lo.x; sm.c.hS[4*tid+1] = lo.y;
        sm.c.hS[4*tid+2] = hi.x; sm.c.hS[4*tid+3] = hi.y;
      }
      __syncthreads();
      // iface: lane-coalesced W_intT4 + uniform h broadcast
      {
        const int o = (tid < 453) ? tid : 452;
        float acc = bintR;
        #pragma unroll 8
        for (int kq = 0; kq < 128; ++kq) {
          float4 w  = *(const float4*)(p.WiT4 + ((size_t)kq*OSTR + o)*4);
          float4 h4 = *(const float4*)&sm.c.hS[kq << 2];
          acc += w.x*h4.x + w.y*h4.y + w.z*h4.z + w.w*h4.w;
        }
        if (tid < 453) sm.c.ifcS[tid] = acc;
      }
      __syncthreads();

      // key pack + key norms (wave 0)
      if (tid < 64) {
        const int w = tid;
        float wk = sm.c.ifcS[260+w];
        float q0 = sm.c.ifcS[w],      q1 = sm.c.ifcS[64+w];
        float q2 = sm.c.ifcS[128+w],  q3 = sm.c.ifcS[192+w];
        float er  = sigm(sm.c.ifcS[325+w]);
        float wvc = sm.c.ifcS[389+w];
        sm.c.kpk[w][0]=wk; sm.c.kpk[w][1]=q0; sm.c.kpk[w][2]=q1; sm.c.kpk[w][3]=q2;
        sm.c.kpk[w][4]=q3; sm.c.kpk[w][5]=er; sm.c.kpk[w][6]=wvc; sm.c.kpk[w][7]=0.f;
        float s0 = wredsum(wk*wk);
        float s1 = wredsum(q0*q0);
        float s2 = wredsum(q1*q1);
        float s3 = wredsum(q2*q2);
        float s4 = wredsum(q3*q3);
        if (w == 0) {
          sm.c.scal[0] = fmaxf(sqrtf(s0), EPSV);
          sm.c.scal[1] = fmaxf(sqrtf(s1), EPSV);
          sm.c.scal[2] = fmaxf(sqrtf(s2), EPSV);
          sm.c.scal[3] = fmaxf(sqrtf(s3), EPSV);
          sm.c.scal[4] = fmaxf(sqrtf(s4), EPSV);
        }
      }
      __syncthreads();

      const int n  = tid & 127;
      const int wh = tid >> 7;      // 0..3 : w-slice of 16

      // pass1: write-key dot + pre-update norm
      {
        float dotw = 0.f, q = 0.f;
        const int w0 = wh*16;
        #pragma unroll
        for (int w = 0; w < 16; ++w) {
          float m = memS[n][w0+w];
          dotw += sm.c.kpk[w0+w][0]*m;
          q    += m*m;
        }
        sm.c.dH[wh][n] = dotw;
        sm.c.qH[wh][n] = q;
      }
      __syncthreads();

      // write softmax over 128 slots (tid<128)
      float a_n = 0.f, e_n = 0.f;
      const float wstr = softp(sm.c.ifcS[324]) + 1.f;
      if (tid < 128) {
        float dot = sm.c.dH[0][n] + sm.c.dH[1][n] + sm.c.dH[2][n] + sm.c.dH[3][n];
        float q2  = sm.c.qH[0][n] + sm.c.qH[1][n] + sm.c.qH[2][n] + sm.c.qH[3][n];
        a_n = wstr * dot / (sm.c.scal[0] * fmaxf(sqrtf(q2), EPSV));
        float mx = wredmax(a_n);
        if ((tid & 63) == 0) sm.c.red2[tid>>6] = mx;
      }
      __syncthreads();
      if (tid < 128) {
        float mx = fmaxf(sm.c.red2[0], sm.c.red2[1]);
        e_n = expf(a_n - mx);
        float s = wredsum(e_n);
        if ((tid & 63) == 0) sm.c.red2[4 + (tid>>6)] = s;
      }
      __syncthreads();
      if (tid < 128)
        sm.c.wwS[n] = e_n / (sm.c.red2[4] + sm.c.red2[5]);
      __syncthreads();

      // pass2: memory update + read-key dots + post norm
      {
        float ww_n = sm.c.wwS[n];
        float nrm=0.f, d0=0.f, d1=0.f, d2=0.f, d3=0.f;
        const int w0 = wh*16;
        #pragma unroll
        for (int w = 0; w < 16; ++w) {
          float4 k0 = *(const float4*)&sm.c.kpk[w0+w][0];
          float4 k1 = *(const float4*)&sm.c.kpk[w0+w][4];
          float m  = memS[n][w0+w];
          float mn = m*(1.f - ww_n*k1.y) + ww_n*k1.z;
          memS[n][w0+w] = mn;
          nrm += mn*mn;
          d0 += k0.y*mn; d1 += k0.z*mn; d2 += k0.w*mn; d3 += k1.x*mn;
        }
        sm.c.nH[wh][n] = nrm;
        sm.c.drH[wh][0][n]=d0; sm.c.drH[wh][1][n]=d1;
        sm.c.drH[wh][2][n]=d2; sm.c.drH[wh][3][n]=d3;
      }
      __syncthreads();

      // read scores (tid<128)
      if (tid < 128) {
        float nrm = sm.c.nH[0][n] + sm.c.nH[1][n] + sm.c.nH[2][n] + sm.c.nH[3][n];
        float inm = 1.f / fmaxf(sqrtf(nrm), EPSV);
        #pragma unroll
        for (int r = 0; r < RR_; ++r) {
          float rstr = softp(sm.c.ifcS[256+r]) + 1.f;
          float dr = sm.c.drH[0][r][n] + sm.c.drH[1][r][n]
                   + sm.c.drH[2][r][n] + sm.c.drH[3][r][n];
          sm.c.rwS[r][n] = rstr * dr * inm / sm.c.scal[1+r];
        }
      }
      __syncthreads();

      // read softmaxes: waves 0..3 = heads
      if (tid < 256) {
        float v0 = sm.c.rwS[wv][b], v1 = sm.c.rwS[wv][b+64];
        float mx = wredmax(fmaxf(v0, v1));
        float e0 = expf(v0-mx), e1 = expf(v1-mx);
        float s  = wredsum(e0+e1);
        sm.c.rwS[wv][b]    = e0/s;
        sm.c.rwS[wv][b+64] = e1/s;
      }
      __syncthreads();

      // rv partials: wave wv -> head wv>>1, n-half wv&1
      {
        const int r  = wv >> 1;
        const int n0 = (wv & 1) * 64;
        float acc = 0.f;
        #pragma unroll 4
        for (int n2 = n0; n2 < n0 + 64; n2 += 4) {
          float4 r4 = *(const float4*)&sm.c.rwS[r][n2];
          acc += r4.x*memS[n2][b]   + r4.y*memS[n2+1][b]
               + r4.z*memS[n2+2][b] + r4.w*memS[n2+3][b];
        }
        sm.c.rvH[wv][b] = acc;
      }
      __syncthreads();
      if (tid < 256) {
        const int r = tid >> 6;
        float acc = sm.c.rvH[2*r][b] + sm.c.rvH[2*r+1][b];
        const int k = r*64 + b;
        cstore1(p.rvp + (k>>2)*256 + bb*4 + (k&3), acc);
      }
    } else if (bi < 128) {
      // stage x_{t+1} (block 64+B owns batch B's row)
      if (t+1 < TT_ && tid < 64) {
        const int B = bi - 64;
        float4 v = *(const float4*)(p.x + (size_t)B*(TT_*DIN_)
                                    + (size_t)(t+1)*DIN_ + 4*tid);
        float* d = p.xbuf + nxt*16384 + tid*256 + B*4;
        cstore2(d,   make_float2(v.x, v.y));
        cstore2(d+2, make_float2(v.z, v.w));
      }
    }
    gridbar(p.bar, ++bk);
  }

  // ================= Output projection (last step only) =================
  if (bi < 64) {
    const int o0 = bi*4;
    if (tid < 256) {
      float acc[4] = {0.f, 0.f, 0.f, 0.f};
      #pragma unroll 4
      for (int kk = 0; kk < 48; ++kk) {
        const int k = wv*192 + kk*4;
        const float* a8 = (k < 512)
          ? (p.hp  + (((k    )>>2)*64 + b)*4)    // TT even -> final h in hp[0]
          : (p.rvp + (((k-512)>>2)*64 + b)*4);
        float2 alo = cload2(a8);
        float2 ahi = cload2(a8 + 2);
        #pragma unroll
        for (int r = 0; r < 4; ++r) {
          float4 w = *(const float4*)(p.Wout + (size_t)(o0+r)*(HH_ + RR_*WWID_) + k);
          acc[r] += w.x*alo.x + w.y*alo.y + w.z*ahi.x + w.w*ahi.y;
        }
      }
      #pragma unroll
      for (int r = 0; r < 4; ++r) sm.redO[wv][r][b] = acc[r];
    }
    __syncthreads();
    if (tid < 64) {
      float4 o4;
      float* po = (float*)&o4;
      #pragma unroll
      for (int r = 0; r < 4; ++r)
        po[r] = sm.redO[0][r][b] + sm.redO[1][r][b] + sm.redO[2][r][b]
              + sm.redO[3][r][b] + p.bout[o0+r];
      *(float4*)(p.out + (size_t)b*DOUT_ + o0) = o4;
    }
  }
}

extern "C" void kernel_launch(void* const* d_in, const int* in_sizes, int n_in,
                              void* d_out, int out_size, void* d_ws, size_t ws_size,
                              hipStream_t stream)
{
  Params prm;
  prm.x    = (const float*)d_in[0];
  prm.Wih  = (const float*)d_in[1];
  prm.Whh  = (const float*)d_in[2];
  prm.bih  = (const float*)d_in[3];
  prm.bhh  = (const float*)d_in[4];
  const float* Wint = (const float*)d_in[5];
  prm.bint = (const float*)d_in[6];
  prm.Wout = (const float*)d_in[7];
  prm.bout = (const float*)d_in[8];
  prm.out  = (float*)d_out;

  float* ws = (float*)d_ws;
  size_t off = 0;
  prm.xbuf = ws + off; off += 2*16384;
  prm.hp   = ws + off; off += 2*32768;
  prm.rvp  = ws + off; off += 16384;
  prm.WiT4 = ws + off; off += (size_t)128*OSTR*4;
  prm.bar  = (unsigned*)(ws + off); off += 2048;

  k_prep_w<<<453, 128, 0, stream>>>(Wint, prm.WiT4);
  k_initbar<<<5, 256, 0, stream>>>(prm.bar);
  k_persist<<<NBLK, NTHR, 0, stream>>>(prm);
}